// Round 11
// baseline (15.948 us; speedup 1.0000x reference)
//
#include <hip/hip_runtime.h>

// Two-kernel structure (fusion measured 2x WORSE: ticket atomics+fence R4=36us,
// R9=30.6us; cooperative launch fails graph capture R5). F ~= 10.5us of the
// 15.5us total is two-node graph-replay overhead; kernel work ~= 5us.
// Kernel 1: 256 blocks x 1024 threads. Each thread loads 4 CONSECUTIVE items
// (float4/int4, coalesced). An 8-lane group holds one 32-item batch (lane
// q8=lane&7 holds local items 4*q8..4*q8+3); a wave64 covers 8 batches.
// Unordered pairs via rotation t=1..15 (each pair once) + t=16 for local
// item<16 (antipodal once): 496 = C(32,2). Pair loss is symmetric
// (sigma(-x)=1-sigma(x)) so unordered mean == reference ordered mean.
// Shuffle CSE explicit: slot (t,c) needs only v=t+c in 1..19 -> 19 bpermutes.
// Rank (5 bits, 0=invalid) packed into score mantissa LSBs (perturbs score
// by <=4e-6; threshold is 1.8e-2). exp2-domain scores:
// sum softplus = ln2*(sum max(y',0) + log2(prod(1+2^-|x'|))), one log2/thread.
__global__ __launch_bounds__(1024) void ranknet_partial_kernel(
    const float4* __restrict__ scores4,
    const int4*   __restrict__ rank4,
    const int4*   __restrict__ mask4,
    float2*       __restrict__ partials)
{
    const int gid  = blockIdx.x * 1024 + threadIdx.x;
    const int lane = threadIdx.x & 63;
    const int wave = threadIdx.x >> 6;

    const float4 s4 = scores4[gid];
    const int4   r4 = rank4[gid];
    const int4   m4 = mask4[gid];

    const float L2E = 1.4426950408889634f;

    unsigned su[4];      // packed: scaled score with rank in low 5 mantissa bits
    int      rj[4];
    float    rjnz[4];
    {
        const float sv[4] = {s4.x, s4.y, s4.z, s4.w};
        const int   rv[4] = {r4.x, r4.y, r4.z, r4.w};
        const int   mv[4] = {m4.x, m4.y, m4.z, m4.w};
        #pragma unroll
        for (int c = 0; c < 4; ++c) {
            const int rr = (mv[c] != 0 && rv[c] > 0) ? rv[c] : 0;
            su[c]   = (__float_as_uint(sv[c] * L2E) & ~31u) | (unsigned)rr;
            rj[c]   = rr;
            rjnz[c] = (rr != 0) ? 1.0f : 0.0f;
        }
    }

    // 19 unique partner words: v = t+c in 1..19, gamma=v&3, delta=v>>2
    unsigned pk[20];
    #pragma unroll
    for (int v = 1; v <= 19; ++v) {
        const int gamma = v & 3;                 // compile-time
        const int delta = v >> 2;                // compile-time
        const int src   = (lane & ~7) | ((lane + delta) & 7);
        pk[v] = __shfl(su[gamma], src);
    }

    float A = 0.0f;   // sum of max(y',0)  (log2 domain)
    float P = 1.0f;   // product of (1+2^-|x'|), gated; <= 2^64
    float C = 0.0f;   // valid-pair count

    const bool low = ((lane & 7) < 4);    // holds local items < 16 (for t=16)

    #pragma unroll
    for (int t = 1; t <= 16; ++t) {
        #pragma unroll
        for (int c = 0; c < 4; ++c) {
            const unsigned pu = pk[t + c];

            const int   ri = (int)(pu & 31u);
            const float x  = __uint_as_float(pu) - __uint_as_float(su[c]);
            const float y  = (ri < rj[c]) ? -x : x;  // softplus arg (log2 dom.)
            const float e  = __builtin_exp2f(-__builtin_fabsf(x));

            float validf = ((ri != 0) && (ri != rj[c])) ? rjnz[c] : 0.0f;
            if (t == 16) validf = low ? validf : 0.0f;

            A  = fmaf(validf, fmaxf(y, 0.0f), A);
            P *= fmaf(validf, e, 1.0f);
            C += validf;
        }
    }

    // per-lane log, then 3-level butterfly within the 8-lane group (one batch)
    float v = A + __builtin_log2f(P);
    #pragma unroll
    for (int off = 1; off <= 4; off <<= 1) {
        v += __shfl_xor(v, off);
        C += __shfl_xor(C, off);
    }
    float pb  = (C > 0.0f) ? (v * 0.6931471805599453f) / C : 0.0f;
    float has = (C > 0.0f) ? 1.0f : 0.0f;

    // sum per-batch means across the wave's 8 groups (8 batches)
    #pragma unroll
    for (int off = 8; off <= 32; off <<= 1) {
        pb  += __shfl_xor(pb, off);
        has += __shfl_xor(has, off);
    }

    __shared__ float2 wpart[16];
    if (lane == 0) wpart[wave] = make_float2(pb, has);
    __syncthreads();
    if (wave == 0) {
        float2 w = (lane < 16) ? wpart[lane] : make_float2(0.0f, 0.0f);
        #pragma unroll
        for (int off = 1; off <= 8; off <<= 1) {
            w.x += __shfl_xor(w.x, off);
            w.y += __shfl_xor(w.y, off);
        }
        if (lane == 0) partials[blockIdx.x] = w;
    }
}

// Single wave, no LDS, no barrier: 256 partials = 4 float2 loads per lane.
__global__ __launch_bounds__(64) void ranknet_finalize_kernel(
    const float2* __restrict__ partials, float* __restrict__ out)
{
    float s = 0.0f, c = 0.0f;
    #pragma unroll
    for (int k = 0; k < 4; ++k) {
        const float2 p = partials[k * 64 + threadIdx.x];
        s += p.x;
        c += p.y;
    }
    #pragma unroll
    for (int off = 32; off > 0; off >>= 1) {
        s += __shfl_xor(s, off);
        c += __shfl_xor(c, off);
    }
    if (threadIdx.x == 0) out[0] = (c > 0.0f) ? (s / c) : 0.0f;
}

extern "C" void kernel_launch(void* const* d_in, const int* in_sizes, int n_in,
                              void* d_out, int out_size, void* d_ws, size_t ws_size,
                              hipStream_t stream) {
    const float4* scores4 = (const float4*)d_in[0];
    const int4*   rank4   = (const int4*)d_in[1];
    const int4*   mask4   = (const int4*)d_in[2];
    float*        out     = (float*)d_out;

    const int total   = in_sizes[0];        // B * 32 = 1,048,576
    const int nblocks = total / 4096;       // 256 blocks, 128 batches each

    float2* partials = (float2*)d_ws;       // 256 * 8B = 2 KB, every slot written

    ranknet_partial_kernel<<<nblocks, 1024, 0, stream>>>(scores4, rank4, mask4, partials);
    ranknet_finalize_kernel<<<1, 64, 0, stream>>>(partials, out);
}

// Round 12
// 15.424 us; speedup vs baseline: 1.0340x; 1.0340x over previous
//
#include <hip/hip_runtime.h>

// FINAL (= R10 config, best measured: 15.52us, absmax 0.0).
// Ledger: total ~15.5us = F~10.5us two-node graph-replay overhead (measured by
// work-scaling solves R1/R2/R6/R7) + kernel1 ~3-3.5us (within ~20% of the
// issue-bound estimate for 16.8M pairs x ~13 VALU + 1 trans) + kernel2 ~1.5us
// (bare launch latency). Launch-overhead-bound, not memory/compute-bound.
// Falsified alternatives: ticket-atomic fusion 30.6-36us (R4/R9: device-scope
// fence + 1024 serialized same-address atomics across non-coherent XCD L2s);
// cooperative launch fails graph capture (R5); DPP restructure +1.2us (R8);
// 1024-thread blocks +0.4us (R11).
//
// Kernel 1: 1024 blocks x 256 threads. Each thread loads 4 CONSECUTIVE items
// (float4/int4, coalesced). An 8-lane group holds one 32-item batch (lane
// q8=lane&7 holds local items 4*q8..4*q8+3); a wave64 covers 8 batches.
// Unordered pairs via rotation t=1..15 (each pair once) + t=16 for local
// item<16 (antipodal once): 496 = C(32,2). Pair loss is symmetric
// (sigma(-x)=1-sigma(x)) so unordered mean == reference ordered mean.
// Shuffle CSE explicit: slot (t,c) needs only v=t+c in 1..19 -> 19 bpermutes.
// Rank (5 bits, 0=invalid) packed into score mantissa LSBs (perturbs score by
// <=4e-6; threshold 1.8e-2). exp2-domain scores:
// sum softplus = ln2*(sum max(y',0) + log2(prod(1+2^-|x'|))), one log2/thread.
__global__ __launch_bounds__(256) void ranknet_partial_kernel(
    const float4* __restrict__ scores4,
    const int4*   __restrict__ rank4,
    const int4*   __restrict__ mask4,
    float2*       __restrict__ partials)
{
    const int gid  = blockIdx.x * 256 + threadIdx.x;
    const int lane = threadIdx.x & 63;
    const int wave = threadIdx.x >> 6;

    const float4 s4 = scores4[gid];
    const int4   r4 = rank4[gid];
    const int4   m4 = mask4[gid];

    const float L2E = 1.4426950408889634f;

    unsigned su[4];      // packed: scaled score with rank in low 5 mantissa bits
    int      rj[4];
    float    rjnz[4];
    {
        const float sv[4] = {s4.x, s4.y, s4.z, s4.w};
        const int   rv[4] = {r4.x, r4.y, r4.z, r4.w};
        const int   mv[4] = {m4.x, m4.y, m4.z, m4.w};
        #pragma unroll
        for (int c = 0; c < 4; ++c) {
            const int rr = (mv[c] != 0 && rv[c] > 0) ? rv[c] : 0;
            su[c]   = (__float_as_uint(sv[c] * L2E) & ~31u) | (unsigned)rr;
            rj[c]   = rr;
            rjnz[c] = (rr != 0) ? 1.0f : 0.0f;
        }
    }

    // 19 unique partner words: v = t+c in 1..19, gamma=v&3, delta=v>>2
    unsigned pk[20];
    #pragma unroll
    for (int v = 1; v <= 19; ++v) {
        const int gamma = v & 3;                 // compile-time
        const int delta = v >> 2;                // compile-time
        const int src   = (lane & ~7) | ((lane + delta) & 7);
        pk[v] = __shfl(su[gamma], src);
    }

    float A = 0.0f;   // sum of max(y',0)  (log2 domain)
    float P = 1.0f;   // product of (1+2^-|x'|), gated; <= 2^64
    float C = 0.0f;   // valid-pair count

    const bool low = ((lane & 7) < 4);    // holds local items < 16 (for t=16)

    #pragma unroll
    for (int t = 1; t <= 16; ++t) {
        #pragma unroll
        for (int c = 0; c < 4; ++c) {
            const unsigned pu = pk[t + c];

            const int   ri = (int)(pu & 31u);
            const float x  = __uint_as_float(pu) - __uint_as_float(su[c]);
            const float y  = (ri < rj[c]) ? -x : x;  // softplus arg (log2 dom.)
            const float e  = __builtin_exp2f(-__builtin_fabsf(x));

            float validf = ((ri != 0) && (ri != rj[c])) ? rjnz[c] : 0.0f;
            if (t == 16) validf = low ? validf : 0.0f;

            A  = fmaf(validf, fmaxf(y, 0.0f), A);
            P *= fmaf(validf, e, 1.0f);
            C += validf;
        }
    }

    // per-lane log, then 3-level butterfly within the 8-lane group (one batch)
    float v = A + __builtin_log2f(P);
    #pragma unroll
    for (int off = 1; off <= 4; off <<= 1) {
        v += __shfl_xor(v, off);
        C += __shfl_xor(C, off);
    }
    float pb  = (C > 0.0f) ? (v * 0.6931471805599453f) / C : 0.0f;
    float has = (C > 0.0f) ? 1.0f : 0.0f;

    // sum per-batch means across the wave's 8 groups (8 batches)
    #pragma unroll
    for (int off = 8; off <= 32; off <<= 1) {
        pb  += __shfl_xor(pb, off);
        has += __shfl_xor(has, off);
    }

    __shared__ float2 wpart[4];
    if (lane == 0) wpart[wave] = make_float2(pb, has);
    __syncthreads();
    if (threadIdx.x == 0) {
        float ps = 0.0f, pc = 0.0f;
        #pragma unroll
        for (int w2 = 0; w2 < 4; ++w2) { ps += wpart[w2].x; pc += wpart[w2].y; }
        partials[blockIdx.x] = make_float2(ps, pc);
    }
}

// Single wave, no LDS, no barrier: 1024 partials = 16 float2 loads per lane.
__global__ __launch_bounds__(64) void ranknet_finalize_kernel(
    const float2* __restrict__ partials, float* __restrict__ out)
{
    float s = 0.0f, c = 0.0f;
    #pragma unroll
    for (int k = 0; k < 16; ++k) {
        const float2 p = partials[k * 64 + threadIdx.x];
        s += p.x;
        c += p.y;
    }
    #pragma unroll
    for (int off = 32; off > 0; off >>= 1) {
        s += __shfl_xor(s, off);
        c += __shfl_xor(c, off);
    }
    if (threadIdx.x == 0) out[0] = (c > 0.0f) ? (s / c) : 0.0f;
}

extern "C" void kernel_launch(void* const* d_in, const int* in_sizes, int n_in,
                              void* d_out, int out_size, void* d_ws, size_t ws_size,
                              hipStream_t stream) {
    const float4* scores4 = (const float4*)d_in[0];
    const int4*   rank4   = (const int4*)d_in[1];
    const int4*   mask4   = (const int4*)d_in[2];
    float*        out     = (float*)d_out;

    const int total   = in_sizes[0];        // B * 32 = 1,048,576
    const int nblocks = total / 1024;       // 1024 blocks, 32 batches each

    float2* partials = (float2*)d_ws;       // 1024 * 8B = 8 KB, every slot written

    ranknet_partial_kernel<<<nblocks, 256, 0, stream>>>(scores4, rank4, mask4, partials);
    ranknet_finalize_kernel<<<1, 64, 0, stream>>>(partials, out);
}